// Round 14
// baseline (163.074 us; speedup 1.0000x reference)
//
#include <hip/hip_runtime.h>
#include <math.h>

// Problem constants (MicroGPT)
constexpr int Bc  = 16;
constexpr int Tc  = 2048;
constexpr int Cc  = 16;
constexpr int Hc  = 2;
constexpr int HSc = 8;
constexpr int Vc  = 256;
constexpr int BT  = Bc * Tc;          // 32768 tokens
constexpr float EPSc = 1e-5f;

// R13 (PASS, 162.9): vectorized tail (conflicts 860K->139K, KF1 faster) but
// KF2 rose to 49us: its 33.5MB logits write runs at 700 GB/s because the
// MFMA head's D-layout stores are 64B chunks at 1KB stride (16 rows per
// instruction). R14: restore the R6-style coalesced VALU head (thread =
// vocab pair {tid,tid+128}, loop 32 tokens, 256B-contiguous wave stores),
// h staged f32 in LDS (broadcast reads, free). Attn/tail/KF1 untouched.

typedef short s8v __attribute__((ext_vector_type(8)));  // 8 bf16 (A/B frag)
typedef float f4v __attribute__((ext_vector_type(4)));  // 4 f32  (C/D frag)

constexpr int WS = 20;                // padded LDS row stride (floats)

__device__ inline float shx(float v, int m) { return __shfl_xor(v, m, 64); }

__device__ inline unsigned short f2bf(float f) {        // f32 -> bf16 RNE
  union { float f; unsigned u; } c; c.f = f;
  unsigned u = c.u + 0x7fffu + ((c.u >> 16) & 1u);
  return (unsigned short)(u >> 16);
}

__device__ inline unsigned cvtpk(float a, float b) {    // pack 2 f32 -> 2 bf16
  unsigned r;
  asm("v_cvt_pk_bf16_f32 %0, %1, %2" : "=v"(r) : "v"(a), "v"(b));
  return r;
}

// ---------------------------------------------------------------------------
// LN helper
// ---------------------------------------------------------------------------
__device__ inline void layernorm16(const float* xr, float* h,
                                   const float* g, const float* b) {
  float m = 0.f;
#pragma unroll
  for (int c = 0; c < Cc; c++) m += xr[c];
  m *= (1.f / Cc);
  float var = 0.f;
#pragma unroll
  for (int c = 0; c < Cc; c++) { float d = xr[c] - m; var += d * d; }
  var *= (1.f / Cc);
  float rs = rsqrtf(var + EPSc);
#pragma unroll
  for (int c = 0; c < Cc; c++) h[c] = (xr[c] - m) * rs * g[c] + b[c];
}

// ---------------------------------------------------------------------------
// K1 variant: 4-lane-coop QKV -> bf16, 64-token block, sv[16][64] staging.
// vt cols permuted per 32-block: key a (local=a&31) stored at
// 8*((a&15)>>2) + 4*((a>>4)&1) + (a&3).
// ---------------------------------------------------------------------------
__device__ inline void qkv_store_bf16(const float* h, const float* swq,
                                      const float* swk, const float* swv,
                                      int bb, int tt, int j,
                                      unsigned short* __restrict__ qb,
                                      unsigned short* __restrict__ kb,
                                      unsigned short* sv) {
  const float pre = 0.35355339059327373f * 1.4426950408889634f;
  int a = tt & 31;
  int col = (tt & 32) | ((((a & 15) >> 2)) << 3) | (((a >> 4) & 1) << 2) |
            (a & 3);                  // 0..63 within the block's 64-col span
#pragma unroll
  for (int hh = 0; hh < Hc; hh++) {
    float q0 = 0.f, q1 = 0.f, k0 = 0.f, k1 = 0.f, v0 = 0.f, v1 = 0.f;
#pragma unroll
    for (int c = 0; c < Cc; c++) {
      float hv = h[c];
      const float* wqp = swq + (hh * Cc + c) * HSc + 2 * j;
      const float* wkp = swk + (hh * Cc + c) * HSc + 2 * j;
      const float* wvp = swv + (hh * Cc + c) * HSc + 2 * j;
      q0 += hv * wqp[0]; q1 += hv * wqp[1];
      k0 += hv * wkp[0]; k1 += hv * wkp[1];
      v0 += hv * wvp[0]; v1 += hv * wvp[1];
    }
    int bh = bb * Hc + hh;
    long rowb = ((long)bh * Tc + tt) * 8 + 2 * j;
    unsigned qp = (unsigned)f2bf(q0 * pre) | ((unsigned)f2bf(q1 * pre) << 16);
    unsigned kp = (unsigned)f2bf(k0) | ((unsigned)f2bf(k1) << 16);
    *(unsigned*)(qb + rowb) = qp;
    *(unsigned*)(kb + rowb) = kp;
    sv[(hh * 8 + 2 * j) * 64 + col]     = f2bf(v0);
    sv[(hh * 8 + 2 * j + 1) * 64 + col] = f2bf(v1);
  }
}

// K1 block-level coalesced writeout of the staged V-transpose tile
__device__ inline void vt_writeout(const unsigned short* sv, int bb, int t0,
                                   int tid, unsigned short* __restrict__ vt) {
  int r  = tid >> 4;                  // row 0..15: hh = r>>3, d = r&7
  int cs = (tid & 15) * 4;            // short offset within 64-col row
  int bh = bb * Hc + (r >> 3);
  int d  = r & 7;
  *(uint2*)(vt + ((long)bh * 8 + d) * Tc + t0 + cs) =
      *(const uint2*)(sv + r * 64 + cs);
}

// ---------------------------------------------------------------------------
// K1) x = tok_emb[idx] + pos_emb ; h = LN1(x) ; qkv -> bf16 buffers.
//     Block 0 zeroes the 64B pad region used for MFMA operand padding.
// ---------------------------------------------------------------------------
__global__ __launch_bounds__(256, 4) void embed_ln_qkv_kernel(
    const int* __restrict__ idx, const float* __restrict__ tok,
    const float* __restrict__ pos,
    const float* __restrict__ wq, const float* __restrict__ wk,
    const float* __restrict__ wv,
    const float* __restrict__ g, const float* __restrict__ b,
    float* __restrict__ x, unsigned short* __restrict__ qb,
    unsigned short* __restrict__ kb, unsigned short* __restrict__ vt,
    unsigned short* __restrict__ zp) {
  __shared__ float swq[256], swk[256], swv[256], sg[Cc], sb[Cc];
  __shared__ unsigned short sv[16 * 64];
  int tid = threadIdx.x;
  if (blockIdx.x == 0 && tid < 16) ((unsigned*)zp)[tid] = 0u;  // 64B zeros
  swq[tid] = wq[tid];
  swk[tid] = wk[tid];
  swv[tid] = wv[tid];
  if (tid < Cc) { sg[tid] = g[tid]; sb[tid] = b[tid]; }
  __syncthreads();

  int tk = blockIdx.x * 64 + (tid >> 2);
  int j  = tid & 3;
  int tt = tk & (Tc - 1);
  int bb = tk >> 11;
  int id = idx[tk];
  float xr[Cc];
  const float4* te = (const float4*)(tok + id * Cc);
  const float4* pe = (const float4*)(pos + tt * Cc);
#pragma unroll
  for (int i = 0; i < 4; i++) {
    float4 a = te[i], p = pe[i];
    xr[4*i] = a.x + p.x; xr[4*i+1] = a.y + p.y;
    xr[4*i+2] = a.z + p.z; xr[4*i+3] = a.w + p.w;
  }
  ((float4*)(x + (long)tk * Cc))[j] =
      make_float4(xr[4*j], xr[4*j+1], xr[4*j+2], xr[4*j+3]);
  float h[Cc];
  layernorm16(xr, h, sg, sb);
  qkv_store_bf16(h, swq, swk, swv, bb, tt, j, qb, kb, sv);
  __syncthreads();
  vt_writeout(sv, bb, (blockIdx.x * 64) & (Tc - 1), tid, vt);
}

// ---------------------------------------------------------------------------
// Attention wave body (R9-proven): one wave = one head (bh), both q-tiles of
// pair (pairId, 127-pairId). Writes normalized O into LDS so[32][WS]
// (row = hf*16 + tile-row, col = wv*8 + d).
// ---------------------------------------------------------------------------
__device__ inline void attn_wave(const unsigned short* __restrict__ qb,
                                 const unsigned short* __restrict__ kb,
                                 const unsigned short* __restrict__ vt,
                                 const unsigned short* __restrict__ zp,
                                 int bh, int pairId, int lane, int wv_,
                                 float* so) {
  int lq = lane & 15;
  int g4 = (lane >> 4) << 2;
  bool real16 = lane < 16;
  bool real8  = lq < 8;
  bool md[4];
#pragma unroll
  for (int r = 0; r < 4; r++) md[r] = (g4 + r) <= lq;

  const f4v zf = {0.f, 0.f, 0.f, 0.f};

#pragma unroll 1
  for (int hf = 0; hf < 2; hf++) {
    int qt = hf ? (127 - pairId) : pairId;
    int q0 = qt << 4;
    int NB = (qt + 2) >> 1;

    s8v qf = *(real16 ? (const s8v*)(qb + ((long)bh * Tc + q0 + lq) * 8)
                      : (const s8v*)zp);
    const unsigned short* kp_ = real16 ? kb + ((long)bh * Tc + lq) * 8 : zp;
    long kts = real16 ? 128 : 0;
    const unsigned short* vp_ =
        real8 ? vt + ((long)bh * 8 + lq) * Tc + (g4 << 1) : zp;
    long vts = real8 ? 32 : 0;

    f4v oacc = zf;
    float lsum = 0.f;

    s8v kf0 = *(const s8v*)kp_;
    s8v kf1 = *(const s8v*)(kp_ + kts);
    kp_ += 2 * kts;
    s8v vf = *(const s8v*)vp_;
    vp_ += vts;

    for (int b = 0; b < NB - 1; b++) {
      s8v kn0 = *(const s8v*)kp_;
      s8v kn1 = *(const s8v*)(kp_ + kts);
      kp_ += 2 * kts;
      s8v vn = *(const s8v*)vp_;
      vp_ += vts;

      f4v st0 = __builtin_amdgcn_mfma_f32_16x16x32_bf16(kf0, qf, zf, 0, 0, 0);
      f4v st1 = __builtin_amdgcn_mfma_f32_16x16x32_bf16(kf1, qf, zf, 0, 0, 0);
      float p00 = __builtin_amdgcn_exp2f(st0[0]);
      float p01 = __builtin_amdgcn_exp2f(st0[1]);
      float p02 = __builtin_amdgcn_exp2f(st0[2]);
      float p03 = __builtin_amdgcn_exp2f(st0[3]);
      float p10 = __builtin_amdgcn_exp2f(st1[0]);
      float p11 = __builtin_amdgcn_exp2f(st1[1]);
      float p12 = __builtin_amdgcn_exp2f(st1[2]);
      float p13 = __builtin_amdgcn_exp2f(st1[3]);
      lsum += ((p00 + p01) + (p02 + p03)) + ((p10 + p11) + (p12 + p13));
      union { unsigned u[4]; s8v s; } pu;
      pu.u[0] = cvtpk(p00, p01);
      pu.u[1] = cvtpk(p02, p03);
      pu.u[2] = cvtpk(p10, p11);
      pu.u[3] = cvtpk(p12, p13);
      oacc = __builtin_amdgcn_mfma_f32_16x16x32_bf16(pu.s, vf, oacc, 0, 0, 0);
      kf0 = kn0; kf1 = kn1; vf = vn;
    }

    {
      f4v st0 = __builtin_amdgcn_mfma_f32_16x16x32_bf16(kf0, qf, zf, 0, 0, 0);
      float p0[4], p1[4];
#pragma unroll
      for (int r = 0; r < 4; r++) p0[r] = __builtin_amdgcn_exp2f(st0[r]);
      if (qt & 1) {
        f4v st1 =
            __builtin_amdgcn_mfma_f32_16x16x32_bf16(kf1, qf, zf, 0, 0, 0);
#pragma unroll
        for (int r = 0; r < 4; r++) {
          float e = __builtin_amdgcn_exp2f(st1[r]);
          p1[r] = md[r] ? e : 0.f;
        }
      } else {
#pragma unroll
        for (int r = 0; r < 4; r++) {
          p0[r] = md[r] ? p0[r] : 0.f;
          p1[r] = 0.f;
        }
      }
      lsum += ((p0[0] + p0[1]) + (p0[2] + p0[3])) +
              ((p1[0] + p1[1]) + (p1[2] + p1[3]));
      union { unsigned u[4]; s8v s; } pu;
      pu.u[0] = cvtpk(p0[0], p0[1]);
      pu.u[1] = cvtpk(p0[2], p0[3]);
      pu.u[2] = cvtpk(p1[0], p1[1]);
      pu.u[3] = cvtpk(p1[2], p1[3]);
      oacc = __builtin_amdgcn_mfma_f32_16x16x32_bf16(pu.s, vf, oacc, 0, 0, 0);
    }

    lsum += shx(lsum, 16);
    lsum += shx(lsum, 32);
    float inv = 1.0f / lsum;
    float invr[4];
#pragma unroll
    for (int r = 0; r < 4; r++) invr[r] = __shfl(inv, g4 + r, 64);
    if (real8) {
      float* ob = so + (hf * 16 + g4) * WS + wv_ * 8 + lq;
#pragma unroll
      for (int r = 0; r < 4; r++) ob[r * WS] = oacc[r] * invr[r];
    }
  }
}

// ---------------------------------------------------------------------------
// Tail core: orow from LDS so ; x += o@wo^T ; x += MLP(LN2). Per-token,
// 4-lane coop; stride-WS float4 weight reads; jj = i*4+j; sw2t transposed.
// ---------------------------------------------------------------------------
__device__ inline void tail_core(
    const float* so, const float* swo, const float* sw1, const float* sw2t,
    const float* sg2, const float* sb2, int tl, int j, float* xr) {
  float orow[Cc];
  {
    const float4* op = (const float4*)(so + tl * WS);
    float4 a = op[0], b = op[1], c = op[2], d = op[3];
    orow[0]=a.x; orow[1]=a.y; orow[2]=a.z; orow[3]=a.w;
    orow[4]=b.x; orow[5]=b.y; orow[6]=b.z; orow[7]=b.w;
    orow[8]=c.x; orow[9]=c.y; orow[10]=c.z; orow[11]=c.w;
    orow[12]=d.x; orow[13]=d.y; orow[14]=d.z; orow[15]=d.w;
  }
  // --- proj, c = 4j..4j+3 (b128 weight reads)
  float xc[4];
#pragma unroll
  for (int qq = 0; qq < 4; qq++) {
    int c = 4 * j + qq;
    const float4* wr = (const float4*)(swo + c * WS);
    float4 wa = wr[0], wb = wr[1], wc = wr[2], wd = wr[3];
    float acc = xr[c]
      + orow[0]*wa.x + orow[1]*wa.y + orow[2]*wa.z + orow[3]*wa.w
      + orow[4]*wb.x + orow[5]*wb.y + orow[6]*wb.z + orow[7]*wb.w
      + orow[8]*wc.x + orow[9]*wc.y + orow[10]*wc.z + orow[11]*wc.w
      + orow[12]*wd.x + orow[13]*wd.y + orow[14]*wd.z + orow[15]*wd.w;
    xc[qq] = acc;
  }
  {
    float p[4];
#pragma unroll
    for (int qq = 0; qq < 4; qq++) p[qq] = shx(xc[qq], 1);
    bool lo = (j & 1) == 0;
    float a8[8], b8[8];
#pragma unroll
    for (int qq = 0; qq < 4; qq++) {
      a8[qq]     = lo ? xc[qq] : p[qq];
      a8[4 + qq] = lo ? p[qq] : xc[qq];
    }
#pragma unroll
    for (int s = 0; s < 8; s++) b8[s] = shx(a8[s], 2);
    bool lo2 = (j & 2) == 0;
#pragma unroll
    for (int s = 0; s < 8; s++) {
      xr[s]     = lo2 ? a8[s] : b8[s];
      xr[8 + s] = lo2 ? b8[s] : a8[s];
    }
  }
  // --- MLP: hidden jj = i*4 + j
  float h[Cc];
  layernorm16(xr, h, sg2, sb2);
  float r[Cc];
#pragma unroll
  for (int c = 0; c < Cc; c++) r[c] = 0.f;
#pragma unroll
  for (int i = 0; i < 16; i++) {
    int jj = i * 4 + j;
    const float4* w1r = (const float4*)(sw1 + jj * WS);
    float4 wa = w1r[0], wb = w1r[1], wc = w1r[2], wd = w1r[3];
    float acc =
        h[0]*wa.x + h[1]*wa.y + h[2]*wa.z + h[3]*wa.w
      + h[4]*wb.x + h[5]*wb.y + h[6]*wb.z + h[7]*wb.w
      + h[8]*wc.x + h[9]*wc.y + h[10]*wc.z + h[11]*wc.w
      + h[12]*wd.x + h[13]*wd.y + h[14]*wd.z + h[15]*wd.w;
    acc = fmaxf(acc, 0.f);
    const float4* w2r = (const float4*)(sw2t + jj * WS);
    float4 va = w2r[0], vb = w2r[1], vc = w2r[2], vd = w2r[3];
    r[0]+=acc*va.x;  r[1]+=acc*va.y;  r[2]+=acc*va.z;  r[3]+=acc*va.w;
    r[4]+=acc*vb.x;  r[5]+=acc*vb.y;  r[6]+=acc*vb.z;  r[7]+=acc*vb.w;
    r[8]+=acc*vc.x;  r[9]+=acc*vc.y;  r[10]+=acc*vc.z; r[11]+=acc*vc.w;
    r[12]+=acc*vd.x; r[13]+=acc*vd.y; r[14]+=acc*vd.z; r[15]+=acc*vd.w;
  }
#pragma unroll
  for (int c = 0; c < Cc; c++) r[c] += shx(r[c], 1);
#pragma unroll
  for (int c = 0; c < Cc; c++) r[c] += shx(r[c], 2);
#pragma unroll
  for (int c = 0; c < Cc; c++) xr[c] += r[c];
}

// ---------------------------------------------------------------------------
// KF1) fused: attn(layer0) + epilogue + LN1 + QKV(layer1 -> qb1/kb1/vt1).
//      128 thr = 2 waves (head 0/1) of pair (p, 127-p), batch b.
// ---------------------------------------------------------------------------
__global__ __launch_bounds__(128, 2) void attn_mid_kernel(
    const unsigned short* __restrict__ qb0,
    const unsigned short* __restrict__ kb0,
    const unsigned short* __restrict__ vt0,
    const unsigned short* __restrict__ zp,
    const float* __restrict__ wo, const float* __restrict__ g2,
    const float* __restrict__ b2, const float* __restrict__ w1,
    const float* __restrict__ w2,
    const float* __restrict__ wq, const float* __restrict__ wk,
    const float* __restrict__ wv, const float* __restrict__ g1,
    const float* __restrict__ b1,
    float* __restrict__ x, unsigned short* __restrict__ qb1,
    unsigned short* __restrict__ kb1, unsigned short* __restrict__ vt1) {
  __shared__ float swo[16 * WS], sw1[64 * WS], sw2t[64 * WS];
  __shared__ float swq[256], swk[256], swv[256];
  __shared__ float sg2[Cc], sb2[Cc], sg1[Cc], sb1[Cc];
  __shared__ float so[32 * WS];
  __shared__ unsigned short sv[2 * 16 * 16];
  int tid = threadIdx.x;
  for (int t = tid; t < 256; t += 128) {
    swq[t] = wq[t]; swk[t] = wk[t]; swv[t] = wv[t];
    swo[(t >> 4) * WS + (t & 15)] = wo[t];
  }
  for (int t = tid; t < 1024; t += 128) {
    sw1[(t >> 4) * WS + (t & 15)] = w1[t];
    sw2t[(t & 63) * WS + (t >> 6)] = w2[t];
  }
  if (tid < Cc) {
    sg2[tid] = g2[tid]; sb2[tid] = b2[tid];
    sg1[tid] = g1[tid]; sb1[tid] = b1[tid];
  }
  __syncthreads();

  int b  = blockIdx.x & 15;
  int p  = blockIdx.x >> 4;           // 0..63
  int wv_ = tid >> 6, lane = tid & 63;
  attn_wave(qb0, kb0, vt0, zp, b * Hc + wv_, p, lane, wv_, so);
  __syncthreads();

  int tl = tid >> 2, j = tid & 3;     // token-local 0..31, lane role
  int qtT = (tl < 16) ? p : (127 - p);
  int tt  = qtT * 16 + (tl & 15);
  long tk = (long)b * Tc + tt;
  float xr[Cc];
  {
    const float4* xp = (const float4*)(x + tk * Cc);
#pragma unroll
    for (int i = 0; i < 4; i++) {
      float4 a = xp[i];
      xr[4*i]=a.x; xr[4*i+1]=a.y; xr[4*i+2]=a.z; xr[4*i+3]=a.w;
    }
  }
  tail_core(so, swo, sw1, sw2t, sg2, sb2, tl, j, xr);
  ((float4*)(x + tk * Cc))[j] =
      make_float4(xr[4*j], xr[4*j+1], xr[4*j+2], xr[4*j+3]);
  float h[Cc];
  layernorm16(xr, h, sg1, sb1);
  // layer-1 qkv: q/k to global, v to dense sv tile [tile][16 rows][16 cols]
  {
    const float pre = 0.35355339059327373f * 1.4426950408889634f;
    int i  = tt & 15;
    int cd = 4 * (i >> 2) + (i & 3);
    int tau = tl >> 4;
#pragma unroll
    for (int hh = 0; hh < Hc; hh++) {
      float q0 = 0.f, q1 = 0.f, k0 = 0.f, k1 = 0.f, v0 = 0.f, v1 = 0.f;
#pragma unroll
      for (int c = 0; c < Cc; c++) {
        float hv = h[c];
        const float* wqp = swq + (hh * Cc + c) * HSc + 2 * j;
        const float* wkp = swk + (hh * Cc + c) * HSc + 2 * j;
        const float* wvp = swv + (hh * Cc + c) * HSc + 2 * j;
        q0 += hv * wqp[0]; q1 += hv * wqp[1];
        k0 += hv * wkp[0]; k1 += hv * wkp[1];
        v0 += hv * wvp[0]; v1 += hv * wvp[1];
      }
      int bh = b * Hc + hh;
      long rowb = ((long)bh * Tc + tt) * 8 + 2 * j;
      *(unsigned*)(qb1 + rowb) =
          (unsigned)f2bf(q0 * pre) | ((unsigned)f2bf(q1 * pre) << 16);
      *(unsigned*)(kb1 + rowb) =
          (unsigned)f2bf(k0) | ((unsigned)f2bf(k1) << 16);
      sv[(tau * 16 + hh * 8 + 2 * j) * 16 + cd]     = f2bf(v0);
      sv[(tau * 16 + hh * 8 + 2 * j + 1) * 16 + cd] = f2bf(v1);
    }
  }
  __syncthreads();
  // vt writeout: 2 tiles x 16 rows x 4 chunks = 128 units = 128 threads
  {
    int tau = tid >> 6, rr = (tid >> 2) & 15, G = tid & 3;
    int qt_ = tau ? (127 - p) : p;
    int bh  = b * Hc + (rr >> 3), d = rr & 7;
    int gcol = ((qt_ & ~1) << 4) + 8 * G + 4 * (qt_ & 1);
    *(uint2*)(vt1 + ((long)bh * 8 + d) * Tc + gcol) =
        *(const uint2*)(sv + (tau * 16 + rr) * 16 + 4 * G);
  }
}

// ---------------------------------------------------------------------------
// KF2) fused: attn(layer1) + epilogue + LNf + tied lm_head (VALU, coalesced).
//      Head: thread tid owns vocab {tid, tid+128}; tok rows (f32) in regs;
//      loops the block's 32 tokens; each wave store = 256B contiguous.
// ---------------------------------------------------------------------------
__global__ __launch_bounds__(128, 2) void attn_lnf_head_kernel(
    const unsigned short* __restrict__ qb1,
    const unsigned short* __restrict__ kb1,
    const unsigned short* __restrict__ vt1,
    const unsigned short* __restrict__ zp,
    const float* __restrict__ wo, const float* __restrict__ g2,
    const float* __restrict__ b2, const float* __restrict__ w1,
    const float* __restrict__ w2, const float* __restrict__ gf,
    const float* __restrict__ bf,
    float* __restrict__ x, const float* __restrict__ tok,
    float* __restrict__ out) {
  __shared__ float swo[16 * WS], sw1[64 * WS], sw2t[64 * WS];
  __shared__ float sg2[Cc], sb2[Cc], sgf[Cc], sbf[Cc];
  __shared__ float so[32 * WS];
  __shared__ float shf[32 * WS];
  int tid = threadIdx.x;
  for (int t = tid; t < 256; t += 128) {
    swo[(t >> 4) * WS + (t & 15)] = wo[t];
  }
  for (int t = tid; t < 1024; t += 128) {
    sw1[(t >> 4) * WS + (t & 15)] = w1[t];
    sw2t[(t & 63) * WS + (t >> 6)] = w2[t];
  }
  if (tid < Cc) {
    sg2[tid] = g2[tid]; sb2[tid] = b2[tid];
    sgf[tid] = gf[tid]; sbf[tid] = bf[tid];
  }
  __syncthreads();

  int b  = blockIdx.x & 15;
  int p  = blockIdx.x >> 4;
  int wv_ = tid >> 6, lane = tid & 63;
  attn_wave(qb1, kb1, vt1, zp, b * Hc + wv_, p, lane, wv_, so);
  __syncthreads();

  int tl = tid >> 2, j = tid & 3;
  int qtT = (tl < 16) ? p : (127 - p);
  int tt  = qtT * 16 + (tl & 15);
  long tk = (long)b * Tc + tt;
  float xr[Cc];
  {
    const float4* xp = (const float4*)(x + tk * Cc);
#pragma unroll
    for (int i = 0; i < 4; i++) {
      float4 a = xp[i];
      xr[4*i]=a.x; xr[4*i+1]=a.y; xr[4*i+2]=a.z; xr[4*i+3]=a.w;
    }
  }
  tail_core(so, swo, sw1, sw2t, sg2, sb2, tl, j, xr);
  float h[Cc];
  layernorm16(xr, h, sgf, sbf);
  *(float4*)(shf + tl * WS + 4 * j) =
      make_float4(h[4*j], h[4*j+1], h[4*j+2], h[4*j+3]);
  __syncthreads();

  // head: thread = vocab pair {tid, tid+128}; 32 tokens from LDS broadcast.
  float4 e0a, e1a, e2a, e3a, e0b, e1b, e2b, e3b;
  {
    const float4* ea = (const float4*)(tok + tid * Cc);
    e0a = ea[0]; e1a = ea[1]; e2a = ea[2]; e3a = ea[3];
    const float4* eb = (const float4*)(tok + (tid + 128) * Cc);
    e0b = eb[0]; e1b = eb[1]; e2b = eb[2]; e3b = eb[3];
  }
#pragma unroll 4
  for (int t = 0; t < 32; t++) {
    const float4* hp = (const float4*)(shf + t * WS);
    float4 h0 = hp[0], h1 = hp[1], h2 = hp[2], h3 = hp[3];
    float a0 = h0.x*e0a.x + h0.y*e0a.y + h0.z*e0a.z + h0.w*e0a.w
             + h1.x*e1a.x + h1.y*e1a.y + h1.z*e1a.z + h1.w*e1a.w
             + h2.x*e2a.x + h2.y*e2a.y + h2.z*e2a.z + h2.w*e2a.w
             + h3.x*e3a.x + h3.y*e3a.y + h3.z*e3a.z + h3.w*e3a.w;
    float a1 = h0.x*e0b.x + h0.y*e0b.y + h0.z*e0b.z + h0.w*e0b.w
             + h1.x*e1b.x + h1.y*e1b.y + h1.z*e1b.z + h1.w*e1b.w
             + h2.x*e2b.x + h2.y*e2b.y + h2.z*e2b.z + h2.w*e2b.w
             + h3.x*e3b.x + h3.y*e3b.y + h3.z*e3b.z + h3.w*e3b.w;
    int qtH = (t < 16) ? p : (127 - p);
    long row = ((long)b * Tc + qtH * 16 + (t & 15)) * Vc;
    out[row + tid]       = a0;
    out[row + tid + 128] = a1;
  }
}

// ---------------------------------------------------------------------------
// launcher
// ---------------------------------------------------------------------------
extern "C" void kernel_launch(void* const* d_in, const int* in_sizes, int n_in,
                              void* d_out, int out_size, void* d_ws,
                              size_t ws_size, hipStream_t stream) {
  const int*   idx  = (const int*)  d_in[0];
  const float* tok  = (const float*)d_in[1];
  const float* pos  = (const float*)d_in[2];
  const float* wq   = (const float*)d_in[3];
  const float* wk   = (const float*)d_in[4];
  const float* wv   = (const float*)d_in[5];
  const float* wo   = (const float*)d_in[6];
  const float* ln1g = (const float*)d_in[7];
  const float* ln1b = (const float*)d_in[8];
  const float* ln2g = (const float*)d_in[9];
  const float* ln2b = (const float*)d_in[10];
  const float* w1   = (const float*)d_in[11];
  const float* w2   = (const float*)d_in[12];
  const float* lnfg = (const float*)d_in[13];
  const float* lnfb = (const float*)d_in[14];
  float* out = (float*)d_out;

  // workspace: x 2MB | qb0/kb0/vt0 1MB | qb1/kb1/vt1 1MB | zp 64B
  float* x = (float*)d_ws;
  unsigned short* qb0 = (unsigned short*)(x + (long)BT * Cc);
  unsigned short* kb0 = qb0 + (long)Bc * Hc * Tc * HSc;
  unsigned short* vt0 = kb0 + (long)Bc * Hc * Tc * HSc;
  unsigned short* qb1 = vt0 + (long)Bc * Hc * Tc * HSc;
  unsigned short* kb1 = qb1 + (long)Bc * Hc * Tc * HSc;
  unsigned short* vt1 = kb1 + (long)Bc * Hc * Tc * HSc;
  unsigned short* zp  = vt1 + (long)Bc * Hc * Tc * HSc;

  embed_ln_qkv_kernel<<<BT / 64, 256, 0, stream>>>(
      idx, tok, pos, wq, wk, wv, ln1g, ln1b, x, qb0, kb0, vt0, zp);
  attn_mid_kernel<<<1024, 128, 0, stream>>>(
      qb0, kb0, vt0, zp, wo, ln2g, ln2b, w1, w2,
      wq + Hc * Cc * HSc, wk + Hc * Cc * HSc, wv + Hc * Cc * HSc,
      ln1g + Cc, ln1b + Cc, x, qb1, kb1, vt1);
  attn_lnf_head_kernel<<<1024, 128, 0, stream>>>(
      qb1, kb1, vt1, zp, wo + Cc * Cc, ln2g + Cc, ln2b + Cc,
      w1 + 4 * Cc * Cc, w2 + 4 * Cc * Cc, lnfg, lnfb, x, tok, out);
}

// Round 15
// 156.250 us; speedup vs baseline: 1.0437x; 1.0437x over previous
//
#include <hip/hip_runtime.h>
#include <math.h>

// Problem constants (MicroGPT)
constexpr int Bc  = 16;
constexpr int Tc  = 2048;
constexpr int Cc  = 16;
constexpr int Hc  = 2;
constexpr int HSc = 8;
constexpr int Vc  = 256;
constexpr int BT  = Bc * Tc;          // 32768 tokens
constexpr float EPSc = 1e-5f;

// R14 (163.1): coalesced head fixed KF2 (left top-5) but total flat ->
// iteration = 43us harness fill + ~115us kernels, all latency-bound at
// 2 waves/SIMD (occupancy 18%, VALU 21%). R15: parallelize the hf loop
// across waves. Fused blocks 128->256 thr (4 waves): wave w handles ONE
// (hf=w>>1, head=w&1) - serial chain halves AND resident waves double
// (4/SIMD). Tail/qkv on tid<128 unchanged; KF2 head = 256 thr x 1 vocab.

typedef short s8v __attribute__((ext_vector_type(8)));  // 8 bf16 (A/B frag)
typedef float f4v __attribute__((ext_vector_type(4)));  // 4 f32  (C/D frag)

constexpr int WS = 20;                // padded LDS row stride (floats)

__device__ inline float shx(float v, int m) { return __shfl_xor(v, m, 64); }

__device__ inline unsigned short f2bf(float f) {        // f32 -> bf16 RNE
  union { float f; unsigned u; } c; c.f = f;
  unsigned u = c.u + 0x7fffu + ((c.u >> 16) & 1u);
  return (unsigned short)(u >> 16);
}

__device__ inline unsigned cvtpk(float a, float b) {    // pack 2 f32 -> 2 bf16
  unsigned r;
  asm("v_cvt_pk_bf16_f32 %0, %1, %2" : "=v"(r) : "v"(a), "v"(b));
  return r;
}

// ---------------------------------------------------------------------------
// LN helper
// ---------------------------------------------------------------------------
__device__ inline void layernorm16(const float* xr, float* h,
                                   const float* g, const float* b) {
  float m = 0.f;
#pragma unroll
  for (int c = 0; c < Cc; c++) m += xr[c];
  m *= (1.f / Cc);
  float var = 0.f;
#pragma unroll
  for (int c = 0; c < Cc; c++) { float d = xr[c] - m; var += d * d; }
  var *= (1.f / Cc);
  float rs = rsqrtf(var + EPSc);
#pragma unroll
  for (int c = 0; c < Cc; c++) h[c] = (xr[c] - m) * rs * g[c] + b[c];
}

// ---------------------------------------------------------------------------
// K1 variant: 4-lane-coop QKV -> bf16, 64-token block, sv[16][64] staging.
// vt cols permuted per 32-block: key a (local=a&31) stored at
// 8*((a&15)>>2) + 4*((a>>4)&1) + (a&3).
// ---------------------------------------------------------------------------
__device__ inline void qkv_store_bf16(const float* h, const float* swq,
                                      const float* swk, const float* swv,
                                      int bb, int tt, int j,
                                      unsigned short* __restrict__ qb,
                                      unsigned short* __restrict__ kb,
                                      unsigned short* sv) {
  const float pre = 0.35355339059327373f * 1.4426950408889634f;
  int a = tt & 31;
  int col = (tt & 32) | ((((a & 15) >> 2)) << 3) | (((a >> 4) & 1) << 2) |
            (a & 3);                  // 0..63 within the block's 64-col span
#pragma unroll
  for (int hh = 0; hh < Hc; hh++) {
    float q0 = 0.f, q1 = 0.f, k0 = 0.f, k1 = 0.f, v0 = 0.f, v1 = 0.f;
#pragma unroll
    for (int c = 0; c < Cc; c++) {
      float hv = h[c];
      const float* wqp = swq + (hh * Cc + c) * HSc + 2 * j;
      const float* wkp = swk + (hh * Cc + c) * HSc + 2 * j;
      const float* wvp = swv + (hh * Cc + c) * HSc + 2 * j;
      q0 += hv * wqp[0]; q1 += hv * wqp[1];
      k0 += hv * wkp[0]; k1 += hv * wkp[1];
      v0 += hv * wvp[0]; v1 += hv * wvp[1];
    }
    int bh = bb * Hc + hh;
    long rowb = ((long)bh * Tc + tt) * 8 + 2 * j;
    unsigned qp = (unsigned)f2bf(q0 * pre) | ((unsigned)f2bf(q1 * pre) << 16);
    unsigned kp = (unsigned)f2bf(k0) | ((unsigned)f2bf(k1) << 16);
    *(unsigned*)(qb + rowb) = qp;
    *(unsigned*)(kb + rowb) = kp;
    sv[(hh * 8 + 2 * j) * 64 + col]     = f2bf(v0);
    sv[(hh * 8 + 2 * j + 1) * 64 + col] = f2bf(v1);
  }
}

// K1 block-level coalesced writeout of the staged V-transpose tile
__device__ inline void vt_writeout(const unsigned short* sv, int bb, int t0,
                                   int tid, unsigned short* __restrict__ vt) {
  int r  = tid >> 4;                  // row 0..15: hh = r>>3, d = r&7
  int cs = (tid & 15) * 4;            // short offset within 64-col row
  int bh = bb * Hc + (r >> 3);
  int d  = r & 7;
  *(uint2*)(vt + ((long)bh * 8 + d) * Tc + t0 + cs) =
      *(const uint2*)(sv + r * 64 + cs);
}

// ---------------------------------------------------------------------------
// K1) x = tok_emb[idx] + pos_emb ; h = LN1(x) ; qkv -> bf16 buffers.
//     Block 0 zeroes the 64B pad region used for MFMA operand padding.
// ---------------------------------------------------------------------------
__global__ __launch_bounds__(256, 4) void embed_ln_qkv_kernel(
    const int* __restrict__ idx, const float* __restrict__ tok,
    const float* __restrict__ pos,
    const float* __restrict__ wq, const float* __restrict__ wk,
    const float* __restrict__ wv,
    const float* __restrict__ g, const float* __restrict__ b,
    float* __restrict__ x, unsigned short* __restrict__ qb,
    unsigned short* __restrict__ kb, unsigned short* __restrict__ vt,
    unsigned short* __restrict__ zp) {
  __shared__ float swq[256], swk[256], swv[256], sg[Cc], sb[Cc];
  __shared__ unsigned short sv[16 * 64];
  int tid = threadIdx.x;
  if (blockIdx.x == 0 && tid < 16) ((unsigned*)zp)[tid] = 0u;  // 64B zeros
  swq[tid] = wq[tid];
  swk[tid] = wk[tid];
  swv[tid] = wv[tid];
  if (tid < Cc) { sg[tid] = g[tid]; sb[tid] = b[tid]; }
  __syncthreads();

  int tk = blockIdx.x * 64 + (tid >> 2);
  int j  = tid & 3;
  int tt = tk & (Tc - 1);
  int bb = tk >> 11;
  int id = idx[tk];
  float xr[Cc];
  const float4* te = (const float4*)(tok + id * Cc);
  const float4* pe = (const float4*)(pos + tt * Cc);
#pragma unroll
  for (int i = 0; i < 4; i++) {
    float4 a = te[i], p = pe[i];
    xr[4*i] = a.x + p.x; xr[4*i+1] = a.y + p.y;
    xr[4*i+2] = a.z + p.z; xr[4*i+3] = a.w + p.w;
  }
  ((float4*)(x + (long)tk * Cc))[j] =
      make_float4(xr[4*j], xr[4*j+1], xr[4*j+2], xr[4*j+3]);
  float h[Cc];
  layernorm16(xr, h, sg, sb);
  qkv_store_bf16(h, swq, swk, swv, bb, tt, j, qb, kb, sv);
  __syncthreads();
  vt_writeout(sv, bb, (blockIdx.x * 64) & (Tc - 1), tid, vt);
}

// ---------------------------------------------------------------------------
// Attention wave body (R9-proven math): one wave = one (head bh, q-tile qt).
// Writes normalized O into LDS so[32][WS] (row = hf*16 + tile-row,
// col = head*8 + d).
// ---------------------------------------------------------------------------
__device__ inline void attn_wave(const unsigned short* __restrict__ qb,
                                 const unsigned short* __restrict__ kb,
                                 const unsigned short* __restrict__ vt,
                                 const unsigned short* __restrict__ zp,
                                 int bh, int qt, int lane, int hd, int hf,
                                 float* so) {
  int lq = lane & 15;
  int g4 = (lane >> 4) << 2;
  bool real16 = lane < 16;
  bool real8  = lq < 8;
  bool md[4];
#pragma unroll
  for (int r = 0; r < 4; r++) md[r] = (g4 + r) <= lq;

  const f4v zf = {0.f, 0.f, 0.f, 0.f};

  int q0 = qt << 4;
  int NB = (qt + 2) >> 1;

  s8v qf = *(real16 ? (const s8v*)(qb + ((long)bh * Tc + q0 + lq) * 8)
                    : (const s8v*)zp);
  const unsigned short* kp_ = real16 ? kb + ((long)bh * Tc + lq) * 8 : zp;
  long kts = real16 ? 128 : 0;
  const unsigned short* vp_ =
      real8 ? vt + ((long)bh * 8 + lq) * Tc + (g4 << 1) : zp;
  long vts = real8 ? 32 : 0;

  f4v oacc = zf;
  float lsum = 0.f;

  s8v kf0 = *(const s8v*)kp_;
  s8v kf1 = *(const s8v*)(kp_ + kts);
  kp_ += 2 * kts;
  s8v vf = *(const s8v*)vp_;
  vp_ += vts;

  for (int b = 0; b < NB - 1; b++) {
    s8v kn0 = *(const s8v*)kp_;
    s8v kn1 = *(const s8v*)(kp_ + kts);
    kp_ += 2 * kts;
    s8v vn = *(const s8v*)vp_;
    vp_ += vts;

    f4v st0 = __builtin_amdgcn_mfma_f32_16x16x32_bf16(kf0, qf, zf, 0, 0, 0);
    f4v st1 = __builtin_amdgcn_mfma_f32_16x16x32_bf16(kf1, qf, zf, 0, 0, 0);
    float p00 = __builtin_amdgcn_exp2f(st0[0]);
    float p01 = __builtin_amdgcn_exp2f(st0[1]);
    float p02 = __builtin_amdgcn_exp2f(st0[2]);
    float p03 = __builtin_amdgcn_exp2f(st0[3]);
    float p10 = __builtin_amdgcn_exp2f(st1[0]);
    float p11 = __builtin_amdgcn_exp2f(st1[1]);
    float p12 = __builtin_amdgcn_exp2f(st1[2]);
    float p13 = __builtin_amdgcn_exp2f(st1[3]);
    lsum += ((p00 + p01) + (p02 + p03)) + ((p10 + p11) + (p12 + p13));
    union { unsigned u[4]; s8v s; } pu;
    pu.u[0] = cvtpk(p00, p01);
    pu.u[1] = cvtpk(p02, p03);
    pu.u[2] = cvtpk(p10, p11);
    pu.u[3] = cvtpk(p12, p13);
    oacc = __builtin_amdgcn_mfma_f32_16x16x32_bf16(pu.s, vf, oacc, 0, 0, 0);
    kf0 = kn0; kf1 = kn1; vf = vn;
  }

  {
    f4v st0 = __builtin_amdgcn_mfma_f32_16x16x32_bf16(kf0, qf, zf, 0, 0, 0);
    float p0[4], p1[4];
#pragma unroll
    for (int r = 0; r < 4; r++) p0[r] = __builtin_amdgcn_exp2f(st0[r]);
    if (qt & 1) {
      f4v st1 = __builtin_amdgcn_mfma_f32_16x16x32_bf16(kf1, qf, zf, 0, 0, 0);
#pragma unroll
      for (int r = 0; r < 4; r++) {
        float e = __builtin_amdgcn_exp2f(st1[r]);
        p1[r] = md[r] ? e : 0.f;
      }
    } else {
#pragma unroll
      for (int r = 0; r < 4; r++) {
        p0[r] = md[r] ? p0[r] : 0.f;
        p1[r] = 0.f;
      }
    }
    lsum += ((p0[0] + p0[1]) + (p0[2] + p0[3])) +
            ((p1[0] + p1[1]) + (p1[2] + p1[3]));
    union { unsigned u[4]; s8v s; } pu;
    pu.u[0] = cvtpk(p0[0], p0[1]);
    pu.u[1] = cvtpk(p0[2], p0[3]);
    pu.u[2] = cvtpk(p1[0], p1[1]);
    pu.u[3] = cvtpk(p1[2], p1[3]);
    oacc = __builtin_amdgcn_mfma_f32_16x16x32_bf16(pu.s, vf, oacc, 0, 0, 0);
  }

  lsum += shx(lsum, 16);
  lsum += shx(lsum, 32);
  float inv = 1.0f / lsum;
  float invr[4];
#pragma unroll
  for (int r = 0; r < 4; r++) invr[r] = __shfl(inv, g4 + r, 64);
  if (real8) {
    float* ob = so + (hf * 16 + g4) * WS + hd * 8 + lq;
#pragma unroll
    for (int r = 0; r < 4; r++) ob[r * WS] = oacc[r] * invr[r];
  }
}

// ---------------------------------------------------------------------------
// Tail core: orow from LDS so ; x += o@wo^T ; x += MLP(LN2). Per-token,
// 4-lane coop; stride-WS float4 weight reads; jj = i*4+j; sw2t transposed.
// ---------------------------------------------------------------------------
__device__ inline void tail_core(
    const float* so, const float* swo, const float* sw1, const float* sw2t,
    const float* sg2, const float* sb2, int tl, int j, float* xr) {
  float orow[Cc];
  {
    const float4* op = (const float4*)(so + tl * WS);
    float4 a = op[0], b = op[1], c = op[2], d = op[3];
    orow[0]=a.x; orow[1]=a.y; orow[2]=a.z; orow[3]=a.w;
    orow[4]=b.x; orow[5]=b.y; orow[6]=b.z; orow[7]=b.w;
    orow[8]=c.x; orow[9]=c.y; orow[10]=c.z; orow[11]=c.w;
    orow[12]=d.x; orow[13]=d.y; orow[14]=d.z; orow[15]=d.w;
  }
  // --- proj, c = 4j..4j+3 (b128 weight reads)
  float xc[4];
#pragma unroll
  for (int qq = 0; qq < 4; qq++) {
    int c = 4 * j + qq;
    const float4* wr = (const float4*)(swo + c * WS);
    float4 wa = wr[0], wb = wr[1], wc = wr[2], wd = wr[3];
    float acc = xr[c]
      + orow[0]*wa.x + orow[1]*wa.y + orow[2]*wa.z + orow[3]*wa.w
      + orow[4]*wb.x + orow[5]*wb.y + orow[6]*wb.z + orow[7]*wb.w
      + orow[8]*wc.x + orow[9]*wc.y + orow[10]*wc.z + orow[11]*wc.w
      + orow[12]*wd.x + orow[13]*wd.y + orow[14]*wd.z + orow[15]*wd.w;
    xc[qq] = acc;
  }
  {
    float p[4];
#pragma unroll
    for (int qq = 0; qq < 4; qq++) p[qq] = shx(xc[qq], 1);
    bool lo = (j & 1) == 0;
    float a8[8], b8[8];
#pragma unroll
    for (int qq = 0; qq < 4; qq++) {
      a8[qq]     = lo ? xc[qq] : p[qq];
      a8[4 + qq] = lo ? p[qq] : xc[qq];
    }
#pragma unroll
    for (int s = 0; s < 8; s++) b8[s] = shx(a8[s], 2);
    bool lo2 = (j & 2) == 0;
#pragma unroll
    for (int s = 0; s < 8; s++) {
      xr[s]     = lo2 ? a8[s] : b8[s];
      xr[8 + s] = lo2 ? b8[s] : a8[s];
    }
  }
  // --- MLP: hidden jj = i*4 + j
  float h[Cc];
  layernorm16(xr, h, sg2, sb2);
  float r[Cc];
#pragma unroll
  for (int c = 0; c < Cc; c++) r[c] = 0.f;
#pragma unroll
  for (int i = 0; i < 16; i++) {
    int jj = i * 4 + j;
    const float4* w1r = (const float4*)(sw1 + jj * WS);
    float4 wa = w1r[0], wb = w1r[1], wc = w1r[2], wd = w1r[3];
    float acc =
        h[0]*wa.x + h[1]*wa.y + h[2]*wa.z + h[3]*wa.w
      + h[4]*wb.x + h[5]*wb.y + h[6]*wb.z + h[7]*wb.w
      + h[8]*wc.x + h[9]*wc.y + h[10]*wc.z + h[11]*wc.w
      + h[12]*wd.x + h[13]*wd.y + h[14]*wd.z + h[15]*wd.w;
    acc = fmaxf(acc, 0.f);
    const float4* w2r = (const float4*)(sw2t + jj * WS);
    float4 va = w2r[0], vb = w2r[1], vc = w2r[2], vd = w2r[3];
    r[0]+=acc*va.x;  r[1]+=acc*va.y;  r[2]+=acc*va.z;  r[3]+=acc*va.w;
    r[4]+=acc*vb.x;  r[5]+=acc*vb.y;  r[6]+=acc*vb.z;  r[7]+=acc*vb.w;
    r[8]+=acc*vc.x;  r[9]+=acc*vc.y;  r[10]+=acc*vc.z; r[11]+=acc*vc.w;
    r[12]+=acc*vd.x; r[13]+=acc*vd.y; r[14]+=acc*vd.z; r[15]+=acc*vd.w;
  }
#pragma unroll
  for (int c = 0; c < Cc; c++) r[c] += shx(r[c], 1);
#pragma unroll
  for (int c = 0; c < Cc; c++) r[c] += shx(r[c], 2);
#pragma unroll
  for (int c = 0; c < Cc; c++) xr[c] += r[c];
}

// ---------------------------------------------------------------------------
// KF1) fused: attn(layer0) + epilogue + LN1 + QKV(layer1 -> qb1/kb1/vt1).
//      256 thr = 4 waves: wave w = (hf=w>>1, head=w&1) of pair (p, 127-p).
//      Tail/qkv on tid<128 (4-lane coop over 32 tokens).
// ---------------------------------------------------------------------------
__global__ __launch_bounds__(256, 4) void attn_mid_kernel(
    const unsigned short* __restrict__ qb0,
    const unsigned short* __restrict__ kb0,
    const unsigned short* __restrict__ vt0,
    const unsigned short* __restrict__ zp,
    const float* __restrict__ wo, const float* __restrict__ g2,
    const float* __restrict__ b2, const float* __restrict__ w1,
    const float* __restrict__ w2,
    const float* __restrict__ wq, const float* __restrict__ wk,
    const float* __restrict__ wv, const float* __restrict__ g1,
    const float* __restrict__ b1,
    float* __restrict__ x, unsigned short* __restrict__ qb1,
    unsigned short* __restrict__ kb1, unsigned short* __restrict__ vt1) {
  __shared__ float swo[16 * WS], sw1[64 * WS], sw2t[64 * WS];
  __shared__ float swq[256], swk[256], swv[256];
  __shared__ float sg2[Cc], sb2[Cc], sg1[Cc], sb1[Cc];
  __shared__ float so[32 * WS];
  __shared__ unsigned short sv[2 * 16 * 16];
  int tid = threadIdx.x;
  {
    int t = tid;
    if (t < 256) {
      swq[t] = wq[t]; swk[t] = wk[t]; swv[t] = wv[t];
      swo[(t >> 4) * WS + (t & 15)] = wo[t];
    }
  }
  for (int t = tid; t < 1024; t += 256) {
    sw1[(t >> 4) * WS + (t & 15)] = w1[t];
    sw2t[(t & 63) * WS + (t >> 6)] = w2[t];
  }
  if (tid < Cc) {
    sg2[tid] = g2[tid]; sb2[tid] = b2[tid];
    sg1[tid] = g1[tid]; sb1[tid] = b1[tid];
  }
  __syncthreads();

  int b  = blockIdx.x & 15;
  int p  = blockIdx.x >> 4;           // 0..63
  int w  = tid >> 6, lane = tid & 63;
  int hd = w & 1, hf = w >> 1;
  int qtw = hf ? (127 - p) : p;
  attn_wave(qb0, kb0, vt0, zp, b * Hc + hd, qtw, lane, hd, hf, so);
  __syncthreads();

  if (tid < 128) {
    int tl = tid >> 2, j = tid & 3;   // token-local 0..31, lane role
    int qtT = (tl < 16) ? p : (127 - p);
    int tt  = qtT * 16 + (tl & 15);
    long tk = (long)b * Tc + tt;
    float xr[Cc];
    {
      const float4* xp = (const float4*)(x + tk * Cc);
#pragma unroll
      for (int i = 0; i < 4; i++) {
        float4 a = xp[i];
        xr[4*i]=a.x; xr[4*i+1]=a.y; xr[4*i+2]=a.z; xr[4*i+3]=a.w;
      }
    }
    tail_core(so, swo, sw1, sw2t, sg2, sb2, tl, j, xr);
    ((float4*)(x + tk * Cc))[j] =
        make_float4(xr[4*j], xr[4*j+1], xr[4*j+2], xr[4*j+3]);
    float h[Cc];
    layernorm16(xr, h, sg1, sb1);
    // layer-1 qkv: q/k to global, v to dense sv tile [tile][16 r][16 c]
    const float pre = 0.35355339059327373f * 1.4426950408889634f;
    int i  = tt & 15;
    int cd = 4 * (i >> 2) + (i & 3);
    int tau = tl >> 4;
#pragma unroll
    for (int hh = 0; hh < Hc; hh++) {
      float q0 = 0.f, q1 = 0.f, k0 = 0.f, k1 = 0.f, v0 = 0.f, v1 = 0.f;
#pragma unroll
      for (int c = 0; c < Cc; c++) {
        float hv = h[c];
        const float* wqp = swq + (hh * Cc + c) * HSc + 2 * j;
        const float* wkp = swk + (hh * Cc + c) * HSc + 2 * j;
        const float* wvp = swv + (hh * Cc + c) * HSc + 2 * j;
        q0 += hv * wqp[0]; q1 += hv * wqp[1];
        k0 += hv * wkp[0]; k1 += hv * wkp[1];
        v0 += hv * wvp[0]; v1 += hv * wvp[1];
      }
      int bh = b * Hc + hh;
      long rowb = ((long)bh * Tc + tt) * 8 + 2 * j;
      *(unsigned*)(qb1 + rowb) =
          (unsigned)f2bf(q0 * pre) | ((unsigned)f2bf(q1 * pre) << 16);
      *(unsigned*)(kb1 + rowb) =
          (unsigned)f2bf(k0) | ((unsigned)f2bf(k1) << 16);
      sv[(tau * 16 + hh * 8 + 2 * j) * 16 + cd]     = f2bf(v0);
      sv[(tau * 16 + hh * 8 + 2 * j + 1) * 16 + cd] = f2bf(v1);
    }
  }
  __syncthreads();
  // vt writeout: 2 tiles x 16 rows x 4 chunks = 128 units (tid<128)
  if (tid < 128) {
    int tau = tid >> 6, rr = (tid >> 2) & 15, G = tid & 3;
    int qt_ = tau ? (127 - p) : p;
    int bh  = b * Hc + (rr >> 3), d = rr & 7;
    int gcol = ((qt_ & ~1) << 4) + 8 * G + 4 * (qt_ & 1);
    *(uint2*)(vt1 + ((long)bh * 8 + d) * Tc + gcol) =
        *(const uint2*)(sv + (tau * 16 + rr) * 16 + 4 * G);
  }
}

// ---------------------------------------------------------------------------
// KF2) fused: attn(layer1) + epilogue + LNf + tied lm_head (VALU, coalesced).
//      256 thr: attn 4 waves; tail tid<128; head thread = vocab tid.
// ---------------------------------------------------------------------------
__global__ __launch_bounds__(256, 4) void attn_lnf_head_kernel(
    const unsigned short* __restrict__ qb1,
    const unsigned short* __restrict__ kb1,
    const unsigned short* __restrict__ vt1,
    const unsigned short* __restrict__ zp,
    const float* __restrict__ wo, const float* __restrict__ g2,
    const float* __restrict__ b2, const float* __restrict__ w1,
    const float* __restrict__ w2, const float* __restrict__ gf,
    const float* __restrict__ bf,
    float* __restrict__ x, const float* __restrict__ tok,
    float* __restrict__ out) {
  __shared__ float swo[16 * WS], sw1[64 * WS], sw2t[64 * WS];
  __shared__ float sg2[Cc], sb2[Cc], sgf[Cc], sbf[Cc];
  __shared__ float so[32 * WS];
  __shared__ float shf[32 * WS];
  int tid = threadIdx.x;
  if (tid < 256) {
    swo[(tid >> 4) * WS + (tid & 15)] = wo[tid];
  }
  for (int t = tid; t < 1024; t += 256) {
    sw1[(t >> 4) * WS + (t & 15)] = w1[t];
    sw2t[(t & 63) * WS + (t >> 6)] = w2[t];
  }
  if (tid < Cc) {
    sg2[tid] = g2[tid]; sb2[tid] = b2[tid];
    sgf[tid] = gf[tid]; sbf[tid] = bf[tid];
  }
  __syncthreads();

  int b  = blockIdx.x & 15;
  int p  = blockIdx.x >> 4;
  int w  = tid >> 6, lane = tid & 63;
  int hd = w & 1, hf = w >> 1;
  int qtw = hf ? (127 - p) : p;
  attn_wave(qb1, kb1, vt1, zp, b * Hc + hd, qtw, lane, hd, hf, so);
  __syncthreads();

  if (tid < 128) {
    int tl = tid >> 2, j = tid & 3;
    int qtT = (tl < 16) ? p : (127 - p);
    int tt  = qtT * 16 + (tl & 15);
    long tk = (long)b * Tc + tt;
    float xr[Cc];
    {
      const float4* xp = (const float4*)(x + tk * Cc);
#pragma unroll
      for (int i = 0; i < 4; i++) {
        float4 a = xp[i];
        xr[4*i]=a.x; xr[4*i+1]=a.y; xr[4*i+2]=a.z; xr[4*i+3]=a.w;
      }
    }
    tail_core(so, swo, sw1, sw2t, sg2, sb2, tl, j, xr);
    float h[Cc];
    layernorm16(xr, h, sgf, sbf);
    *(float4*)(shf + tl * WS + 4 * j) =
        make_float4(h[4*j], h[4*j+1], h[4*j+2], h[4*j+3]);
  }
  __syncthreads();

  // head: thread = vocab tid (256 thr); 32 tokens from LDS broadcast.
  float4 e0, e1, e2, e3;
  {
    const float4* ep = (const float4*)(tok + tid * Cc);
    e0 = ep[0]; e1 = ep[1]; e2 = ep[2]; e3 = ep[3];
  }
#pragma unroll 4
  for (int t = 0; t < 32; t++) {
    const float4* hp = (const float4*)(shf + t * WS);
    float4 h0 = hp[0], h1 = hp[1], h2 = hp[2], h3 = hp[3];
    float a0 = h0.x*e0.x + h0.y*e0.y + h0.z*e0.z + h0.w*e0.w
             + h1.x*e1.x + h1.y*e1.y + h1.z*e1.z + h1.w*e1.w
             + h2.x*e2.x + h2.y*e2.y + h2.z*e2.z + h2.w*e2.w
             + h3.x*e3.x + h3.y*e3.y + h3.z*e3.z + h3.w*e3.w;
    int qtH = (t < 16) ? p : (127 - p);
    long row = ((long)b * Tc + qtH * 16 + (t & 15)) * Vc;
    out[row + tid] = a0;
  }
}

// ---------------------------------------------------------------------------
// launcher
// ---------------------------------------------------------------------------
extern "C" void kernel_launch(void* const* d_in, const int* in_sizes, int n_in,
                              void* d_out, int out_size, void* d_ws,
                              size_t ws_size, hipStream_t stream) {
  const int*   idx  = (const int*)  d_in[0];
  const float* tok  = (const float*)d_in[1];
  const float* pos  = (const float*)d_in[2];
  const float* wq   = (const float*)d_in[3];
  const float* wk   = (const float*)d_in[4];
  const float* wv   = (const float*)d_in[5];
  const float* wo   = (const float*)d_in[6];
  const float* ln1g = (const float*)d_in[7];
  const float* ln1b = (const float*)d_in[8];
  const float* ln2g = (const float*)d_in[9];
  const float* ln2b = (const float*)d_in[10];
  const float* w1   = (const float*)d_in[11];
  const float* w2   = (const float*)d_in[12];
  const float* lnfg = (const float*)d_in[13];
  const float* lnfb = (const float*)d_in[14];
  float* out = (float*)d_out;

  // workspace: x 2MB | qb0/kb0/vt0 1MB | qb1/kb1/vt1 1MB | zp 64B
  float* x = (float*)d_ws;
  unsigned short* qb0 = (unsigned short*)(x + (long)BT * Cc);
  unsigned short* kb0 = qb0 + (long)Bc * Hc * Tc * HSc;
  unsigned short* vt0 = kb0 + (long)Bc * Hc * Tc * HSc;
  unsigned short* qb1 = vt0 + (long)Bc * Hc * Tc * HSc;
  unsigned short* kb1 = qb1 + (long)Bc * Hc * Tc * HSc;
  unsigned short* vt1 = kb1 + (long)Bc * Hc * Tc * HSc;
  unsigned short* zp  = vt1 + (long)Bc * Hc * Tc * HSc;

  embed_ln_qkv_kernel<<<BT / 64, 256, 0, stream>>>(
      idx, tok, pos, wq, wk, wv, ln1g, ln1b, x, qb0, kb0, vt0, zp);
  attn_mid_kernel<<<1024, 256, 0, stream>>>(
      qb0, kb0, vt0, zp, wo, ln2g, ln2b, w1, w2,
      wq + Hc * Cc * HSc, wk + Hc * Cc * HSc, wv + Hc * Cc * HSc,
      ln1g + Cc, ln1b + Cc, x, qb1, kb1, vt1);
  attn_lnf_head_kernel<<<1024, 256, 0, stream>>>(
      qb1, kb1, vt1, zp, wo + Cc * Cc, ln2g + Cc, ln2b + Cc,
      w1 + 4 * Cc * Cc, w2 + 4 * Cc * Cc, lnfg, lnfb, x, tok, out);
}